// Round 9
// baseline (627.725 us; speedup 1.0000x reference)
//
#include <hip/hip_runtime.h>

typedef unsigned short u16;
typedef __attribute__((ext_vector_type(8))) short bf16x8;   // 8 bf16 = 4 VGPRs (MFMA A/B frag)
typedef __attribute__((ext_vector_type(4))) short bf16x4;
typedef __attribute__((ext_vector_type(4))) float f32x4;    // MFMA C/D frag

__device__ __forceinline__ float bf2f(u16 u){ union { unsigned int i; float f; } v; v.i = ((unsigned int)u) << 16; return v.f; }
__device__ __forceinline__ u16 f2bf(float f){ union { float f; unsigned int i; } v; v.f = f; unsigned int r = v.i + 0x7fffu + ((v.i >> 16) & 1u); return (u16)(r >> 16); }

#define MFMA(a,b,c) __builtin_amdgcn_mfma_f32_16x16x32_bf16((a),(b),(c),0,0,0)

// async global->LDS, 16B per lane. LDS dest is wave-uniform base + lane*16.
__device__ __forceinline__ void gl_lds16(const u16* g, u16* l){
  __builtin_amdgcn_global_load_lds((const __attribute__((address_space(1))) unsigned int*)g,
                                   (__attribute__((address_space(3))) unsigned int*)l, 16, 0, 0);
}

// ---------------- Kernel 1: merged GroupNorm stats + weight bf16 conversion ----------------
// blocks [0,512): stats (mean,rstd) per (b,group); blocks [512,1536): f32->bf16 weight pack.
__global__ __launch_bounds__(256) void k_prep(const float* __restrict__ x, float* __restrict__ stats,
                                              const float* __restrict__ wq, const float* __restrict__ wp,
                                              u16* __restrict__ wout){
  __shared__ float ls[4], lq[4];
  const int tid = threadIdx.x;
  if (blockIdx.x < 512){
    const int bg = blockIdx.x;
    const float4* p = (const float4*)(x + (size_t)bg * 65536);
    float s = 0.f, sq = 0.f;
    for (int i = 0; i < 64; ++i){
      float4 v = p[tid + i*256];
      s += v.x + v.y + v.z + v.w;
      sq += v.x*v.x + v.y*v.y + v.z*v.z + v.w*v.w;
    }
#pragma unroll
    for (int d = 32; d > 0; d >>= 1){ s += __shfl_down(s, d, 64); sq += __shfl_down(sq, d, 64); }
    if ((tid & 63) == 0){ ls[tid>>6] = s; lq[tid>>6] = sq; }
    __syncthreads();
    if (tid == 0){
      float S = ls[0]+ls[1]+ls[2]+ls[3];
      float Q = lq[0]+lq[1]+lq[2]+lq[3];
      float mean = S * (1.f/65536.f);
      float var  = Q * (1.f/65536.f) - mean*mean;
      stats[bg*2]   = mean;
      stats[bg*2+1] = rsqrtf(var + 1e-5f);
    }
  } else {
    const int base = ((blockIdx.x - 512)*256 + tid) * 4;     // 1024 blocks -> 1,048,576 elems
    float4 v;
    if (base < 786432) v = *(const float4*)(wq + base);
    else               v = *(const float4*)(wp + (base - 786432));
    bf16x4 o;
    o[0] = (short)f2bf(v.x); o[1] = (short)f2bf(v.y); o[2] = (short)f2bf(v.z); o[3] = (short)f2bf(v.w);
    *(bf16x4*)(wout + base) = o;
  }
}

// ---------------- Kernel 2: GN affine + transpose -> Xnt[b][l][c] (bf16) ----------------
__global__ __launch_bounds__(256) void k_gn_t(const float* __restrict__ x, const float* __restrict__ stats,
                                              const float* __restrict__ gamma, const float* __restrict__ beta,
                                              u16* __restrict__ xnt){
  __shared__ u16 tile[64*72];                      // [c][l], stride 72
  const int l0 = blockIdx.x*64, c0 = blockIdx.y*64, b = blockIdx.z;
  const int tid = threadIdx.x;
#pragma unroll
  for (int i = 0; i < 2; ++i){
    int v = tid + i*256; int cc = v >> 3, seg = v & 7;
    int c = c0 + cc;
    float mu = stats[(b*32 + (c>>4))*2], rs = stats[(b*32 + (c>>4))*2 + 1];
    float ga = gamma[c] * rs;
    float be = beta[c] - mu * ga;                  // (x-mu)*rs*g + b = x*ga + be
    const float* px = x + ((size_t)(b*512 + c))*4096 + l0 + seg*8;
    float4 a0 = *(const float4*)px;
    float4 a1 = *(const float4*)(px + 4);
    bf16x8 ov;
    ov[0]=(short)f2bf(a0.x*ga+be); ov[1]=(short)f2bf(a0.y*ga+be);
    ov[2]=(short)f2bf(a0.z*ga+be); ov[3]=(short)f2bf(a0.w*ga+be);
    ov[4]=(short)f2bf(a1.x*ga+be); ov[5]=(short)f2bf(a1.y*ga+be);
    ov[6]=(short)f2bf(a1.z*ga+be); ov[7]=(short)f2bf(a1.w*ga+be);
    *(bf16x8*)&tile[cc*72 + seg*8] = ov;
  }
  __syncthreads();
#pragma unroll
  for (int i = 0; i < 2; ++i){
    int v = tid + i*256; int ll = v >> 3, seg = v & 7;
    bf16x8 ov;
#pragma unroll
    for (int j = 0; j < 8; ++j) ov[j] = (short)tile[(seg*8 + j)*72 + ll];
    *(bf16x8*)(xnt + ((size_t)(b*4096 + l0 + ll))*512 + c0 + seg*8) = ov;
  }
}

// ---------------- Kernel 3: QKV GEMM (r2-proven m97-style: 128x128 tile, 2-barrier, BK=64) ----------------
// Measured: 128.6 us, MfmaUtil 35% — the m97-structure ceiling; all pipelining grafts measured slower.
__global__ __launch_bounds__(256,2) void k_qkv(const u16* __restrict__ xnt, const u16* __restrict__ wq,
                                               const float* __restrict__ bq,
                                               u16* __restrict__ Qt, u16* __restrict__ Kt, u16* __restrict__ Vh){
  __shared__ u16 smem[17408];                      // 34816 B: sA[0:8192)+sW[8192:16384); epilogue reuses as 128x136
  u16* sA = smem;
  u16* sW = smem + 8192;
  const int l0 = blockIdx.x*128, o0 = blockIdx.y*128, b = blockIdx.z;
  const int tid = threadIdx.x, wv = tid>>6, lane = tid&63, g = lane>>4, r = lane&15;
  const int wm = wv>>1, wn = wv&1;
  const u16* Ab = xnt + ((size_t)(b*4096 + l0))*512;
  const u16* Wb = wq  + (size_t)o0*512;
  int srow[4], scol[4];
#pragma unroll
  for (int j = 0; j < 4; ++j){
    int s = wv*256 + j*64 + lane;
    srow[j] = s >> 3;
    scol[j] = ((s & 7) ^ (srow[j] & 7)) * 8;
  }
  f32x4 acc[4][4];
#pragma unroll
  for (int mt = 0; mt < 4; ++mt)
#pragma unroll
    for (int nt = 0; nt < 4; ++nt) acc[mt][nt] = (f32x4){0.f,0.f,0.f,0.f};

  const int key = r & 7;
  for (int c0 = 0; c0 < 512; c0 += 64){
    __syncthreads();                               // prev tile's reads done
#pragma unroll
    for (int j = 0; j < 4; ++j){
      u16* ldst = &smem[(wv*256 + j*64)*8];        // wave-uniform
      gl_lds16(Ab + (size_t)srow[j]*512 + c0 + scol[j], ldst);
      gl_lds16(Wb + (size_t)srow[j]*512 + c0 + scol[j], ldst + 8192);
    }
    __syncthreads();                               // staged data visible
#pragma unroll
    for (int half = 0; half < 2; ++half){
      bf16x8 a[4], w[4];
#pragma unroll
      for (int mt = 0; mt < 4; ++mt){ int R = wm*64 + mt*16 + r; a[mt] = *(const bf16x8*)&sA[(R*8 + ((half*4+g) ^ key))*8]; }
#pragma unroll
      for (int nt = 0; nt < 4; ++nt){ int R = wn*64 + nt*16 + r; w[nt] = *(const bf16x8*)&sW[(R*8 + ((half*4+g) ^ key))*8]; }
#pragma unroll
      for (int mt = 0; mt < 4; ++mt)
#pragma unroll
        for (int nt = 0; nt < 4; ++nt) acc[mt][nt] = MFMA(a[mt], w[nt], acc[mt][nt]);
    }
  }
  __syncthreads();                                 // last tile's reads done; reuse smem for epilogue
  const int t   = blockIdx.y >> 2;                 // 0=Q 1=K 2=V
  const int cp0 = (blockIdx.y & 3)*128;            // c' base within tensor
  const int h   = blockIdx.x >> 2;                 // head = l0/512
  const int lh0 = (blockIdx.x & 3)*128;            // pos base within head
#pragma unroll
  for (int nt = 0; nt < 4; ++nt){
    const int ol = wn*64 + nt*16 + r;              // o local (= c')
    const float bi = bq[o0 + ol];
#pragma unroll
    for (int mt = 0; mt < 4; ++mt){
      const int ll = wm*64 + mt*16 + g*4;          // l local (D rows, 4 consecutive)
      if (t == 2){                                 // V: LDS [o][l]
        bf16x4 pk;
#pragma unroll
        for (int rr = 0; rr < 4; ++rr) pk[rr] = (short)f2bf(acc[mt][nt][rr] + bi);
        *(bf16x4*)&smem[ol*136 + ll] = pk;
      } else {                                     // Q/K: LDS [l][o] (transpose)
#pragma unroll
        for (int rr = 0; rr < 4; ++rr) smem[(ll + rr)*136 + ol] = f2bf(acc[mt][nt][rr] + bi);
      }
    }
  }
  __syncthreads();
  const size_t bh = (size_t)(b*8 + h);
  u16* dst = (t == 0) ? Qt : Kt;
#pragma unroll
  for (int i = 0; i < 8; ++i){
    int v = tid + i*256; int row = v >> 4, seg = v & 15;
    bf16x8 d = *(const bf16x8*)&smem[row*136 + seg*8];
    if (t == 2){
      *(bf16x8*)(Vh + (bh*512 + cp0 + row)*512 + lh0 + seg*8) = d;      // Vh[b][h][c'][pos]
    } else {
      *(bf16x8*)(dst + (bh*512 + lh0 + row)*512 + cp0 + seg*8) = d;     // Qt/Kt[b][h][pos][c']
    }
  }
}

// ---------------- Kernel 4: fused attention, QBLK=64, 512 threads, 8 waves, 2 blocks/CU ----------------
// 1024 blocks, XCD-chunked (each bh's 8 q-tiles run back-to-back on one XCD -> K/V L2-hot).
// LDS 76KB: P[64][512] bf16 (64KB) + Q step buffer (8KB) + red scratch (4KB) -> 2 blocks/CU
// (vs 135KB/1 block before). K is NOT LDS-staged: each wave reads its K frags global->reg
// (per-wave-exclusive k-range 64, L2-resident). Q staged per 64-c step, r2-k_qkv geometry
// (128B rows, source-side XOR key row&7, conflict-free ds_read_b128), plain 2-barrier loop —
// the barrier drain is covered by the co-resident second block (m114 wave-level overlap).
// launch_bounds(512,4) caps VGPR at 128 so 2 blocks (16 waves/CU) fit the register file.
__global__ __launch_bounds__(512,4) void k_attn(const u16* __restrict__ Qt, const u16* __restrict__ Kt,
                                                const u16* __restrict__ Vh, u16* __restrict__ At){
  extern __shared__ __align__(16) u16 smem[];      // 77824 B dynamic
  u16*  sQ   = smem + 32768;                       // byte 65536: Q[64][64] step buffer (8KB)
  float* sMax = (float*)(smem + 36864);            // byte 73728: [q 64][wv 8]
  float* sSum = sMax + 512;                        // byte 75776: [q 64][wv 8]
  const int wgid = blockIdx.x;                     // 0..1023; XCD-chunked remap (1024%8==0 -> bijective)
  const int orig = (wgid & 7)*128 + (wgid >> 3);
  const int b = orig >> 6, h = (orig >> 3) & 7, q0 = (orig & 7) * 64;
  const int bh = b*8 + h;
  const int tid = threadIdx.x, wv = tid>>6, lane = tid&63, g = lane>>4, r = lane&15;
  const size_t base = (size_t)bh * 262144;
  const u16* Qb = Qt + base + (size_t)q0*512;
  const u16* Kb = Kt + base;
  const u16* Vb = Vh + base;

  // Q staging: 64 rows x 8 chunks(16B) = 512 chunks; 1 chunk per thread.
  // row = tid>>3, phys chunk = tid&7, logical chunk = phys ^ (row&7) (source-side pre-swizzle).
  const int qrow = tid >> 3;
  const u16* qsrc = Qb + (size_t)qrow*512 + (((tid & 7) ^ (qrow & 7)) * 8);
  u16* qdst = sQ + wv*512;                         // wave-uniform base; lane*16B implicit

  f32x4 s[4][4];                                   // q-frag mt, k-frag nt (wave k-range = wv*64)
#pragma unroll
  for (int mt = 0; mt < 4; ++mt)
#pragma unroll
    for (int nt = 0; nt < 4; ++nt) s[mt][nt] = (f32x4){0.f,0.f,0.f,0.f};

  const int key = r & 7;
  // ---- Phase 1: S[q 64][k 512] = sum_c Q K^T; 8 steps of 64 c; K direct global->reg
  for (int cs = 0; cs < 8; ++cs){
    const int c0 = cs * 64;
    __syncthreads();                               // prev step's sQ reads done
    gl_lds16(qsrc + c0, qdst);
    __syncthreads();                               // sQ visible (drain also completes K loads below)
#pragma unroll
    for (int half = 0; half < 2; ++half){
      bf16x8 a[4], kb[4];
#pragma unroll
      for (int nt = 0; nt < 4; ++nt)
        kb[nt] = *(const bf16x8*)(Kb + (size_t)(wv*64 + nt*16 + r)*512 + c0 + half*32 + g*8);
#pragma unroll
      for (int mt = 0; mt < 4; ++mt){ int R = mt*16 + r; a[mt] = *(const bf16x8*)&sQ[(R*8 + ((half*4+g) ^ key))*8]; }
      __builtin_amdgcn_s_setprio(1);
#pragma unroll
      for (int mt = 0; mt < 4; ++mt)
#pragma unroll
        for (int nt = 0; nt < 4; ++nt) s[mt][nt] = MFMA(a[mt], kb[nt], s[mt][nt]);
      __builtin_amdgcn_s_setprio(0);
    }
  }

  // ---- softmax over k=512 (D layout: q = mt*16+g*4+rr, k = wv*64+nt*16+r)
#pragma unroll
  for (int mt = 0; mt < 4; ++mt)
#pragma unroll
    for (int nt = 0; nt < 4; ++nt)
#pragma unroll
      for (int rr = 0; rr < 4; ++rr) s[mt][nt][rr] *= 0.125f;

  float mx[4][4];
#pragma unroll
  for (int mt = 0; mt < 4; ++mt)
#pragma unroll
    for (int rr = 0; rr < 4; ++rr){
      float m = s[mt][0][rr];
#pragma unroll
      for (int nt = 1; nt < 4; ++nt) m = fmaxf(m, s[mt][nt][rr]);
      m = fmaxf(m, __shfl_xor(m, 1, 64)); m = fmaxf(m, __shfl_xor(m, 2, 64));
      m = fmaxf(m, __shfl_xor(m, 4, 64)); m = fmaxf(m, __shfl_xor(m, 8, 64));
      mx[mt][rr] = m;
    }
  if (r == 0){
#pragma unroll
    for (int mt = 0; mt < 4; ++mt)
#pragma unroll
      for (int rr = 0; rr < 4; ++rr) sMax[(mt*16 + g*4 + rr)*8 + wv] = mx[mt][rr];
  }
  __syncthreads();
#pragma unroll
  for (int mt = 0; mt < 4; ++mt)
#pragma unroll
    for (int rr = 0; rr < 4; ++rr){
      const int q = mt*16 + g*4 + rr;
      float4 v0 = *(const float4*)&sMax[q*8];
      float4 v1 = *(const float4*)&sMax[q*8 + 4];
      mx[mt][rr] = fmaxf(fmaxf(fmaxf(v0.x, v0.y), fmaxf(v0.z, v0.w)),
                         fmaxf(fmaxf(v1.x, v1.y), fmaxf(v1.z, v1.w)));
    }
  float inv[4][4];
#pragma unroll
  for (int mt = 0; mt < 4; ++mt)
#pragma unroll
    for (int rr = 0; rr < 4; ++rr){
      float t = 0.f;
#pragma unroll
      for (int nt = 0; nt < 4; ++nt){
        float e = __expf(s[mt][nt][rr] - mx[mt][rr]);
        s[mt][nt][rr] = e; t += e;
      }
      t += __shfl_xor(t, 1, 64); t += __shfl_xor(t, 2, 64);
      t += __shfl_xor(t, 4, 64); t += __shfl_xor(t, 8, 64);
      inv[mt][rr] = t;                             // wave-partial sum
    }
  if (r == 0){
#pragma unroll
    for (int mt = 0; mt < 4; ++mt)
#pragma unroll
      for (int rr = 0; rr < 4; ++rr) sSum[(mt*16 + g*4 + rr)*8 + wv] = inv[mt][rr];
  }
  __syncthreads();
#pragma unroll
  for (int mt = 0; mt < 4; ++mt)
#pragma unroll
    for (int rr = 0; rr < 4; ++rr){
      const int q = mt*16 + g*4 + rr;
      float4 v0 = *(const float4*)&sSum[q*8];
      float4 v1 = *(const float4*)&sSum[q*8 + 4];
      inv[mt][rr] = 1.f / (v0.x + v0.y + v0.z + v0.w + v1.x + v1.y + v1.z + v1.w);
    }
  // write P (bf16, chunk-swizzled ch^(q&7)) into P region [0, 32768 u16)
  {
    const int kx7 = r & 7, chb = wv*8 + (r >> 3);  // k>>3 base: k = wv*64 + nt*16 + r
#pragma unroll
    for (int mt = 0; mt < 4; ++mt)
#pragma unroll
      for (int rr = 0; rr < 4; ++rr){
        const int q = mt*16 + g*4 + rr;
        const int ro = q*512, qx = q & 7;
        const float iv = inv[mt][rr];
#pragma unroll
        for (int nt = 0; nt < 4; ++nt){
          const int ch = chb + nt*2;
          smem[ro + ((ch ^ qx) * 8) + kx7] = f2bf(s[mt][nt][rr] * iv);
        }
      }
  }
  // early V prefetch: issue first fragments before the barrier so latency hides under it
  const u16* Vw = Vb + (size_t)(wv*64 + r)*512 + g*8;
  bf16x8 vf[2][4];
#pragma unroll
  for (int mt = 0; mt < 4; ++mt) vf[0][mt] = *(const bf16x8*)(Vw + mt*8192);
  __syncthreads();

  // ---- Phase 2: A[c 512][q 64] = sum_k V[c][k] P[q][k]; wave owns c-range 64, barrier-free
  f32x4 o[4][4];
#pragma unroll
  for (int mt = 0; mt < 4; ++mt)
#pragma unroll
    for (int nt = 0; nt < 4; ++nt) o[mt][nt] = (f32x4){0.f,0.f,0.f,0.f};
#pragma unroll
  for (int kk = 0; kk < 16; ++kk){
    if (kk < 15){
#pragma unroll
      for (int mt = 0; mt < 4; ++mt) vf[(kk+1)&1][mt] = *(const bf16x8*)(Vw + mt*8192 + (kk+1)*32);
    }
    bf16x8 pp[4];
#pragma unroll
    for (int nt = 0; nt < 4; ++nt){
      const int q = nt*16 + r;
      pp[nt] = *(const bf16x8*)&smem[q*512 + (((kk*4 + g) ^ (r & 7)) * 8)];
    }
    __builtin_amdgcn_s_setprio(1);
#pragma unroll
    for (int mt = 0; mt < 4; ++mt)
#pragma unroll
      for (int nt = 0; nt < 4; ++nt) o[mt][nt] = MFMA(vf[kk&1][mt], pp[nt], o[mt][nt]);
    __builtin_amdgcn_s_setprio(0);
  }
  __syncthreads();                                  // all P reads done; reuse P region as At bounce

  // bounce o -> LDS [q][c] (same chunk swizzle), then coalesced copy out
#pragma unroll
  for (int mt = 0; mt < 4; ++mt){
    const int c = wv*64 + mt*16 + g*4;
    const int ch = c >> 3, cl = c & 7;
#pragma unroll
    for (int nt = 0; nt < 4; ++nt){
      const int q = nt*16 + r;
      bf16x4 pk;
#pragma unroll
      for (int rr = 0; rr < 4; ++rr) pk[rr] = (short)f2bf(o[mt][nt][rr]);
      *(bf16x4*)&smem[q*512 + ((ch ^ (r & 7)) * 8) + cl] = pk;
    }
  }
  __syncthreads();
  u16* Ad = At + ((size_t)(bh*512 + q0))*512;      // exactly this block's Q rows (in-place alias)
#pragma unroll
  for (int i = 0; i < 8; ++i){
    const int idx = tid + i*512, q = idx >> 6, ch = idx & 63;
    bf16x8 d = *(const bf16x8*)&smem[q*512 + ((ch ^ (q & 7)) * 8)];
    *(bf16x8*)(Ad + (size_t)q*512 + ch*8) = d;
  }
}

// ---------------- Kernel 5: proj GEMM (r2-proven m97-style) + f32 residual -> f32 out ----------------
__global__ __launch_bounds__(256,2) void k_proj(const u16* __restrict__ At, const u16* __restrict__ wp,
                                                const float* __restrict__ bpr, const float* __restrict__ x,
                                                float* __restrict__ out){
  __shared__ u16 smem[17408];
  u16* sA = smem;
  u16* sW = smem + 8192;
  const int l0 = blockIdx.x*128, o0 = blockIdx.y*128, b = blockIdx.z;
  const int tid = threadIdx.x, wv = tid>>6, lane = tid&63, g = lane>>4, r = lane&15;
  const int wm = wv>>1, wn = wv&1;
  const u16* Ab = At + ((size_t)(b*4096 + l0))*512;
  const u16* Wb = wp + (size_t)o0*512;
  int srow[4], scol[4];
#pragma unroll
  for (int j = 0; j < 4; ++j){
    int s = wv*256 + j*64 + lane;
    srow[j] = s >> 3;
    scol[j] = ((s & 7) ^ (srow[j] & 7)) * 8;
  }
  f32x4 acc[4][4];
#pragma unroll
  for (int mt = 0; mt < 4; ++mt)
#pragma unroll
    for (int nt = 0; nt < 4; ++nt) acc[mt][nt] = (f32x4){0.f,0.f,0.f,0.f};
  const int key = r & 7;
  for (int c0 = 0; c0 < 512; c0 += 64){
    __syncthreads();
#pragma unroll
    for (int j = 0; j < 4; ++j){
      u16* ldst = &smem[(wv*256 + j*64)*8];
      gl_lds16(Ab + (size_t)srow[j]*512 + c0 + scol[j], ldst);
      gl_lds16(Wb + (size_t)srow[j]*512 + c0 + scol[j], ldst + 8192);
    }
    __syncthreads();
#pragma unroll
    for (int half = 0; half < 2; ++half){
      bf16x8 a[4], w[4];
#pragma unroll
      for (int mt = 0; mt < 4; ++mt){ int R = wm*64 + mt*16 + r; a[mt] = *(const bf16x8*)&sA[(R*8 + ((half*4+g) ^ key))*8]; }
#pragma unroll
      for (int nt = 0; nt < 4; ++nt){ int R = wn*64 + nt*16 + r; w[nt] = *(const bf16x8*)&sW[(R*8 + ((half*4+g) ^ key))*8]; }
#pragma unroll
      for (int mt = 0; mt < 4; ++mt)
#pragma unroll
        for (int nt = 0; nt < 4; ++nt) acc[mt][nt] = MFMA(a[mt], w[nt], acc[mt][nt]);
    }
  }
  __syncthreads();
#pragma unroll
  for (int nt = 0; nt < 4; ++nt){
    const int ol = wn*64 + nt*16 + r;
    const float bi = bpr[o0 + ol];
#pragma unroll
    for (int mt = 0; mt < 4; ++mt){
      const int ll = wm*64 + mt*16 + g*4;
      bf16x4 pk;
#pragma unroll
      for (int rr = 0; rr < 4; ++rr) pk[rr] = (short)f2bf(acc[mt][nt][rr] + bi);
      *(bf16x4*)&smem[ol*136 + ll] = pk;            // LDS [o][l]
    }
  }
  __syncthreads();
#pragma unroll
  for (int i = 0; i < 16; ++i){
    int v = tid + i*256; int row = v >> 5, seg = v & 31;   // row=o-local 0..127, seg*4 = l-local
    bf16x4 d = *(const bf16x4*)&smem[row*136 + seg*4];
    const size_t gi = ((size_t)(b*512 + o0 + row))*4096 + l0 + seg*4;
    float4 xv = *(const float4*)(x + gi);
    float4 ov;
    ov.x = bf2f((u16)d[0]) + xv.x;
    ov.y = bf2f((u16)d[1]) + xv.y;
    ov.z = bf2f((u16)d[2]) + xv.z;
    ov.w = bf2f((u16)d[3]) + xv.w;
    *(float4*)(out + gi) = ov;
  }
}

extern "C" void kernel_launch(void* const* d_in, const int* in_sizes, int n_in,
                              void* d_out, int out_size, void* d_ws, size_t ws_size,
                              hipStream_t stream) {
  (void)in_sizes; (void)n_in; (void)out_size; (void)ws_size;
  const float* x     = (const float*)d_in[0];
  const float* gamma = (const float*)d_in[1];
  const float* beta  = (const float*)d_in[2];
  const float* wqkv  = (const float*)d_in[3];
  const float* bqkv  = (const float*)d_in[4];
  const float* wproj = (const float*)d_in[5];
  const float* bproj = (const float*)d_in[6];
  float* out = (float*)d_out;
  char* ws = (char*)d_ws;

  float* stats = (float*)ws;                        // 8 KB
  u16* W16  = (u16*)(ws + 8192);                    // wqkv16 (786432) + wproj16 (262144)
  u16* Wq16 = W16;
  u16* Wp16 = W16 + 786432;
  u16* Qt = (u16*)(ws + 8192 + 2097152);            // 64 MiB  [b][h][pos][c]  (becomes At in place)
  u16* Kt = Qt + (size_t)33554432;                  // 64 MiB  [b][h][pos][c]
  u16* Vh = Kt + (size_t)33554432;                  // 64 MiB  [b][h][c][pos]
  u16* At = Qt;                                     // in-place alias (see k_attn)
  u16* Xnt = (u16*)d_out;                           // bf16 staging in d_out (dead before k_proj writes)

  static bool attn_attr = false;
  if (!attn_attr){
    hipFuncSetAttribute((const void*)k_attn, hipFuncAttributeMaxDynamicSharedMemorySize, 77824);
    attn_attr = true;
  }

  k_prep<<<1536, 256, 0, stream>>>(x, stats, wqkv, wproj, W16);
  k_gn_t<<<dim3(64,8,16), 256, 0, stream>>>(x, stats, gamma, beta, Xnt);
  k_qkv<<<dim3(32,12,16), 256, 0, stream>>>(Xnt, Wq16, bqkv, Qt, Kt, Vh);
  k_attn<<<1024, 512, 77824, stream>>>(Qt, Kt, Vh, At);
  k_proj<<<dim3(32,4,16), 256, 0, stream>>>(At, Wp16, bproj, x, out);
}